// Round 7
// baseline (119.085 us; speedup 1.0000x reference)
//
#include <hip/hip_runtime.h>
#include <cmath>

// SSIM fused kernel v7: full-height column-strip design.
// - Block = 32-col x 512-row strip of one plane; grid 16x48 = 768 blocks
//   (exactly 3/CU, no tail, 3 cold starts per CU instead of 24).
// - Circular 74-row LDS buffer of 4 h-convolved planes (37888 B). 8 chunks of
//   64 output rows; per-chunk phase-1 is EXACTLY 2 items/thread (perfect
//   balance); halo rows computed once per strip (522 rows vs 592 tiled).
// - T14 prefetch: chunk c+1's item-0 global loads issue before phase-2 of
//   chunk c; the barrier's implicit vmcnt(0) lands after phase-2 compute.
// - Parity-preserving circular layout: slot s = L % 74 (74 even -> parity
//   kept); phys = s/2 (even) or 37 + s/2 (odd). Phase-2's 2-row-per-thread
//   window reads contiguous phys rows -> 0 bank conflicts (measured v5/v6).

#define W 512
#define H 512
#define OWD 502
#define OHD 502
#define TILEC 32
#define CHUNK 64
#define BUF 74
#define ESPLIT 37
#define NVALID 12096192     // 48 * 502 * 502
#define NSTRIP 16
#define NPLANE 48
#define NPART (NSTRIP * NPLANE * 4)

struct Weights { float g[11]; };

__global__ __launch_bounds__(256) void ssim_kernel(
    const float* __restrict__ x, const float* __restrict__ y,
    float* __restrict__ partial, float* __restrict__ accum, int use_atomic, Weights wt)
{
    __shared__ __align__(16) float hb[4][BUF][TILEC];

    const int tid = threadIdx.x;
    const int c0 = blockIdx.x * TILEC;
    const size_t plane = (size_t)blockIdx.y * (W * H);
    const float* xp = x + plane;
    const float* yp = y + plane;

    // Load 16 x-cols + 16 y-cols (4 float4 each) for logical row L, col group cgl.
    auto load8 = [&](int L, int cgl, float4* a, float4* b) {
        if (L < H) {
            const float* xr = xp + (size_t)L * W;
            const float* yr = yp + (size_t)L * W;
            #pragma unroll
            for (int q = 0; q < 4; q++) {
                const int gc = c0 + cgl + 4 * q;
                if (gc < W) {  // W%4==0, gc%4==0 -> float4 fully in or out
                    a[q] = *(const float4*)(xr + gc);
                    b[q] = *(const float4*)(yr + gc);
                } else {
                    a[q] = make_float4(0.f, 0.f, 0.f, 0.f);
                    b[q] = make_float4(0.f, 0.f, 0.f, 0.f);
                }
            }
        } else {
            #pragma unroll
            for (int q = 0; q < 4; q++) {
                a[q] = make_float4(0.f, 0.f, 0.f, 0.f);
                b[q] = make_float4(0.f, 0.f, 0.f, 0.f);
            }
        }
    };

    // Horizontal conv of one row item; store 4 planes to circular buffer.
    auto hstore = [&](int L, int cgl, const float4* a, const float4* b) {
        float xv[16], yv[16];
        #pragma unroll
        for (int q = 0; q < 4; q++) {
            xv[4*q+0] = a[q].x; xv[4*q+1] = a[q].y; xv[4*q+2] = a[q].z; xv[4*q+3] = a[q].w;
            yv[4*q+0] = b[q].x; yv[4*q+1] = b[q].y; yv[4*q+2] = b[q].z; yv[4*q+3] = b[q].w;
        }
        float ssv[16], xyv[16];
        #pragma unroll
        for (int j = 0; j < 16; j++) {
            ssv[j] = xv[j] * xv[j] + yv[j] * yv[j];
            xyv[j] = xv[j] * yv[j];
        }
        float m1[4] = {0.f,0.f,0.f,0.f}, m2[4] = {0.f,0.f,0.f,0.f};
        float ms[4] = {0.f,0.f,0.f,0.f}, mx[4] = {0.f,0.f,0.f,0.f};
        #pragma unroll
        for (int k = 0; k < 11; k++) {
            const float w = wt.g[k];
            #pragma unroll
            for (int j = 0; j < 4; j++) {
                m1[j] += w * xv[j + k];
                m2[j] += w * yv[j + k];
                ms[j] += w * ssv[j + k];
                mx[j] += w * xyv[j + k];
            }
        }
        const int s = L % BUF;                       // 74 even -> parity kept
        const int p = (s & 1) ? (ESPLIT + (s >> 1)) : (s >> 1);
        *(float4*)&hb[0][p][cgl] = make_float4(m1[0], m1[1], m1[2], m1[3]);
        *(float4*)&hb[1][p][cgl] = make_float4(m2[0], m2[1], m2[2], m2[3]);
        *(float4*)&hb[2][p][cgl] = make_float4(ms[0], ms[1], ms[2], ms[3]);
        *(float4*)&hb[3][p][cgl] = make_float4(mx[0], mx[1], mx[2], mx[3]);
    };

    // ---- Prologue: rows 0..73 (592 items, 2.31 iters -- once per block).
    for (int i = tid; i < BUF * 8; i += 256) {
        float4 a[4], b[4];
        const int L = i >> 3, cgl = (i & 7) << 2;
        load8(L, cgl, a, b);
        hstore(L, cgl, a, b);
    }
    __syncthreads();

    // ---- Steady loop: 8 chunks of 64 output rows.
    float lsum = 0.f;
    const int rp = tid >> 3;          // row pair 0..31
    const int cg = (tid & 7) << 2;    // col group
    const int r0i = tid >> 3;         // phase-1 item row (same formula)
    int sbase = (2 * rp) % BUF;       // slot of row 2rp at chunk 0

    for (int c = 0; c < 8; ++c) {
        const int Lb = CHUNK * c + BUF;          // first new row for next chunk
        const bool pf = (c < 7);
        float4 pa[4], pb[4];
        if (pf) load8(Lb + r0i, cg, pa, pb);     // prefetch item-0 loads

        // -- Phase 2: vertical conv + SSIM for output rows 64c+2rp, +1.
        {
            float a[4][2][4];
            #pragma unroll
            for (int j = 0; j < 4; j++)
                #pragma unroll
                for (int rr = 0; rr < 2; rr++)
                    #pragma unroll
                    for (int e = 0; e < 4; e++) a[j][rr][e] = 0.f;

            #pragma unroll
            for (int t = 0; t < 12; t++) {
                int s = sbase + t;
                if (s >= BUF) s -= BUF;
                const int prow = (s & 1) ? (ESPLIT + (s >> 1)) : (s >> 1);
                float4 v[4];
                #pragma unroll
                for (int j = 0; j < 4; j++) v[j] = *(const float4*)&hb[j][prow][cg];
                if (t <= 10) {
                    const float w = wt.g[t];
                    #pragma unroll
                    for (int j = 0; j < 4; j++) {
                        a[j][0][0] += w * v[j].x; a[j][0][1] += w * v[j].y;
                        a[j][0][2] += w * v[j].z; a[j][0][3] += w * v[j].w;
                    }
                }
                if (t >= 1) {
                    const float w = wt.g[t - 1];
                    #pragma unroll
                    for (int j = 0; j < 4; j++) {
                        a[j][1][0] += w * v[j].x; a[j][1][1] += w * v[j].y;
                        a[j][1][2] += w * v[j].z; a[j][1][3] += w * v[j].w;
                    }
                }
            }

            const float C1 = 1e-4f;   // (0.01*1)^2
            const float C2 = 9e-4f;   // (0.03*1)^2
            const int ob = CHUNK * c;
            #pragma unroll
            for (int rr = 0; rr < 2; rr++) {
                const int orow = ob + 2 * rp + rr;
                if (orow < OHD) {
                    #pragma unroll
                    for (int e = 0; e < 4; e++) {
                        const int ocol = c0 + cg + e;
                        if (ocol < OWD) {
                            const float mu1 = a[0][rr][e], mu2 = a[1][rr][e];
                            const float mu12 = mu1 * mu2;
                            const float mu1s = mu1 * mu1;
                            const float mu2s = mu2 * mu2;
                            const float sss = a[2][rr][e] - mu1s - mu2s;
                            const float s12 = a[3][rr][e] - mu12;
                            const float num = (2.f * mu12 + C1) * (2.f * s12 + C2);
                            const float den = (mu1s + mu2s + C1) * (sss + C2);
                            lsum += num / den;
                        }
                    }
                }
            }
        }
        __syncthreads();   // all phase-2 reads done; safe to overwrite slots

        if (pf) {
            hstore(Lb + r0i, cg, pa, pb);               // item 0 (prefetched)
            float4 a2[4], b2[4];
            const int r1 = (tid + 256) >> 3;            // item 1: rows 32..63
            load8(Lb + r1, cg, a2, b2);
            hstore(Lb + r1, cg, a2, b2);
        }
        __syncthreads();   // new rows visible for next chunk

        sbase += CHUNK;                                  // advance circular base
        if (sbase >= BUF) sbase -= BUF;
    }

    // ---- Per-wave reduction; one partial (or atomic) per wave.
    #pragma unroll
    for (int off = 32; off > 0; off >>= 1) lsum += __shfl_down(lsum, off, 64);
    if ((tid & 63) == 0) {
        const int wave = tid >> 6;
        const int bid = blockIdx.y * NSTRIP + blockIdx.x;
        if (use_atomic) unsafeAtomicAdd(accum, lsum);
        else partial[bid * 4 + wave] = lsum;
    }
}

__global__ __launch_bounds__(1024) void reduce_kernel(
    const float* __restrict__ partial, float* __restrict__ out)
{
    __shared__ float ws[16];
    float s = 0.f;
    for (int i = threadIdx.x; i < NPART; i += 1024) s += partial[i];
    #pragma unroll
    for (int off = 32; off > 0; off >>= 1) s += __shfl_down(s, off, 64);
    const int wave = threadIdx.x >> 6;
    if ((threadIdx.x & 63) == 0) ws[wave] = s;
    __syncthreads();
    if (threadIdx.x == 0) {
        float t = 0.f;
        #pragma unroll
        for (int i = 0; i < 16; i++) t += ws[i];
        out[0] = t * (1.0f / (float)NVALID);
    }
}

__global__ void finalize_kernel(const float* __restrict__ accum, float* __restrict__ out) {
    out[0] = accum[0] * (1.0f / (float)NVALID);
}

extern "C" void kernel_launch(void* const* d_in, const int* in_sizes, int n_in,
                              void* d_out, int out_size, void* d_ws, size_t ws_size,
                              hipStream_t stream) {
    const float* x = (const float*)d_in[0];
    const float* y = (const float*)d_in[1];
    float* out = (float*)d_out;
    float* ws = (float*)d_ws;

    // Gaussian window, computed in double like the numpy reference, cast to f32.
    Weights wt;
    {
        double g[11], s = 0.0;
        for (int i = 0; i < 11; i++) {
            double d = (double)(i - 5);
            g[i] = exp(-(d * d) / (2.0 * 1.5 * 1.5));
            s += g[i];
        }
        for (int i = 0; i < 11; i++) wt.g[i] = (float)(g[i] / s);
    }

    dim3 grid(NSTRIP, NPLANE);
    const int use_atomic = (ws_size < (size_t)NPART * sizeof(float)) ? 1 : 0;
    if (use_atomic) {
        hipMemsetAsync(ws, 0, sizeof(float), stream);
        ssim_kernel<<<grid, 256, 0, stream>>>(x, y, ws, ws, 1, wt);
        finalize_kernel<<<1, 1, 0, stream>>>(ws, out);
    } else {
        ssim_kernel<<<grid, 256, 0, stream>>>(x, y, ws, ws, 0, wt);
        reduce_kernel<<<1, 1024, 0, stream>>>(ws, out);
    }
}

// Round 8
// 93.614 us; speedup vs baseline: 1.2721x; 1.2721x over previous
//
#include <hip/hip_runtime.h>
#include <cmath>

// SSIM fused kernel v8 = v6 + three stall fixes:
// 1. Phase-1 software pipeline: issue item0+item1 global loads before any
//    conv; item2 (80/256 threads) loads issue under item1's conv. Shortens
//    the straggler critical path and hides vmem latency under compute.
// 2. s_setprio(1) around phase-2 compute (blocks at different phases per CU
//    -> compute waves win issue arbitration; m191-positive regime).
// 3. Parallel tail reduction: 24 blocks x 1024 -> 24 sums -> 64-thread final
//    (replaces single-block serial-latency reduce). Deterministic, no atomics.

#define W 512
#define H 512
#define OWD 502
#define OHD 502
#define TILEC 32
#define TILER 64
#define INR 74            // logical halo'd rows; phys: 37 even + 37 odd
#define ESPLIT 37         // phys offset of odd rows
#define NVALID 12096192   // 48 * 502 * 502
#define NBLKX 16
#define NBLKY 8
#define NPART (NBLKX * NBLKY * 48 * 4)   // 24576 = one partial per wave
#define NRB 24                            // reduce1 blocks (24*1024 = NPART)

struct Weights { float g[11]; };

__global__ __launch_bounds__(256) void ssim_kernel(
    const float* __restrict__ x, const float* __restrict__ y,
    float* __restrict__ partial, float* __restrict__ accum, int use_atomic, Weights wt)
{
    __shared__ __align__(16) float hb[4][INR][TILEC];

    const int tid = threadIdx.x;
    const int r0 = blockIdx.y * TILER;
    const int c0 = blockIdx.x * TILEC;
    const size_t plane = (size_t)blockIdx.z * (W * H);
    const float* xp = x + plane;
    const float* yp = y + plane;

    // Load 16 x + 16 y values (4 float4 each) for phase-1 item i.
    auto loadF = [&](int i, float4* a, float4* b) {
        const int p = i >> 3;
        const int cg = (i & 7) << 2;
        const int lr = (p < ESPLIT) ? (2 * p) : (2 * (p - ESPLIT) + 1);
        const int gr = r0 + lr;
        if (gr < H) {
            const float* xr = xp + (size_t)gr * W;
            const float* yr = yp + (size_t)gr * W;
            #pragma unroll
            for (int q = 0; q < 4; q++) {
                const int gc = c0 + cg + 4 * q;
                if (gc < W) {  // W%4==0, gc%4==0 -> float4 fully in or out
                    a[q] = *(const float4*)(xr + gc);
                    b[q] = *(const float4*)(yr + gc);
                } else {
                    a[q] = make_float4(0.f, 0.f, 0.f, 0.f);
                    b[q] = make_float4(0.f, 0.f, 0.f, 0.f);
                }
            }
        } else {
            #pragma unroll
            for (int q = 0; q < 4; q++) {
                a[q] = make_float4(0.f, 0.f, 0.f, 0.f);
                b[q] = make_float4(0.f, 0.f, 0.f, 0.f);
            }
        }
    };

    // Horizontal conv of item i; store 4 planes to hb.
    auto convStore = [&](int i, const float4* a, const float4* b) {
        const int p = i >> 3;
        const int cg = (i & 7) << 2;
        float xv[16], yv[16];
        #pragma unroll
        for (int q = 0; q < 4; q++) {
            xv[4*q+0] = a[q].x; xv[4*q+1] = a[q].y; xv[4*q+2] = a[q].z; xv[4*q+3] = a[q].w;
            yv[4*q+0] = b[q].x; yv[4*q+1] = b[q].y; yv[4*q+2] = b[q].z; yv[4*q+3] = b[q].w;
        }
        float ssv[16], xyv[16];
        #pragma unroll
        for (int j = 0; j < 16; j++) {
            ssv[j] = xv[j] * xv[j] + yv[j] * yv[j];
            xyv[j] = xv[j] * yv[j];
        }
        float m1[4] = {0.f,0.f,0.f,0.f}, m2[4] = {0.f,0.f,0.f,0.f};
        float ms[4] = {0.f,0.f,0.f,0.f}, mx[4] = {0.f,0.f,0.f,0.f};
        #pragma unroll
        for (int k = 0; k < 11; k++) {
            const float w = wt.g[k];
            #pragma unroll
            for (int j = 0; j < 4; j++) {
                m1[j] += w * xv[j + k];
                m2[j] += w * yv[j + k];
                ms[j] += w * ssv[j + k];
                mx[j] += w * xyv[j + k];
            }
        }
        *(float4*)&hb[0][p][cg] = make_float4(m1[0], m1[1], m1[2], m1[3]);
        *(float4*)&hb[1][p][cg] = make_float4(m2[0], m2[1], m2[2], m2[3]);
        *(float4*)&hb[2][p][cg] = make_float4(ms[0], ms[1], ms[2], ms[3]);
        *(float4*)&hb[3][p][cg] = make_float4(mx[0], mx[1], mx[2], mx[3]);
    };

    // ---- Phase 1, software-pipelined: 592 items = 2/thread + 80 extras.
    {
        const int i0 = tid, i1 = tid + 256, i2 = tid + 512;
        const bool has3 = (i2 < INR * 8);
        float4 A0[4], B0[4], A1[4], B1[4];
        loadF(i0, A0, B0);          // both items' loads in flight before
        loadF(i1, A1, B1);          // any conv consumes them
        convStore(i0, A0, B0);
        if (has3) loadF(i2, A0, B0);   // straggler loads hide under conv1
        convStore(i1, A1, B1);
        if (has3) convStore(i2, A0, B0);
    }
    __syncthreads();

    // ---- Phase 2: vertical pass + SSIM. All 256 threads: 2 rows x 4 cols.
    float lsum = 0.f;
    {
        const int rp = tid >> 3;         // row pair 0..31 -> rows 2rp, 2rp+1
        const int cg = (tid & 7) << 2;   // col group
        float a[4][2][4];
        #pragma unroll
        for (int j = 0; j < 4; j++)
            #pragma unroll
            for (int rr = 0; rr < 2; rr++)
                #pragma unroll
                for (int e = 0; e < 4; e++) a[j][rr][e] = 0.f;

        __builtin_amdgcn_s_setprio(1);
        #pragma unroll
        for (int t = 0; t < 12; t++) {
            // logical row 2rp+t -> phys: even at rp+t/2, odd at ESPLIT+rp+(t-1)/2
            const int prow = ((t & 1) == 0) ? (rp + (t >> 1))
                                            : (ESPLIT + rp + (t >> 1));
            float4 v[4];
            #pragma unroll
            for (int j = 0; j < 4; j++) v[j] = *(const float4*)&hb[j][prow][cg];
            if (t <= 10) {   // tap for output row 0 (compile-time)
                const float w = wt.g[t];
                #pragma unroll
                for (int j = 0; j < 4; j++) {
                    a[j][0][0] += w * v[j].x; a[j][0][1] += w * v[j].y;
                    a[j][0][2] += w * v[j].z; a[j][0][3] += w * v[j].w;
                }
            }
            if (t >= 1) {    // tap for output row 1 (compile-time)
                const float w = wt.g[t - 1];
                #pragma unroll
                for (int j = 0; j < 4; j++) {
                    a[j][1][0] += w * v[j].x; a[j][1][1] += w * v[j].y;
                    a[j][1][2] += w * v[j].z; a[j][1][3] += w * v[j].w;
                }
            }
        }

        const float C1 = 1e-4f;   // (0.01*1)^2
        const float C2 = 9e-4f;   // (0.03*1)^2
        #pragma unroll
        for (int rr = 0; rr < 2; rr++) {
            const int orow = r0 + 2 * rp + rr;
            if (orow < OHD) {
                #pragma unroll
                for (int e = 0; e < 4; e++) {
                    const int ocol = c0 + cg + e;
                    if (ocol < OWD) {
                        const float mu1 = a[0][rr][e], mu2 = a[1][rr][e];
                        const float mu12 = mu1 * mu2;
                        const float mu1s = mu1 * mu1;
                        const float mu2s = mu2 * mu2;
                        const float sss = a[2][rr][e] - mu1s - mu2s;  // s11+s22
                        const float s12 = a[3][rr][e] - mu12;
                        const float num = (2.f * mu12 + C1) * (2.f * s12 + C2);
                        const float den = (mu1s + mu2s + C1) * (sss + C2);
                        lsum += num / den;
                    }
                }
            }
        }
        __builtin_amdgcn_s_setprio(0);
    }

    // ---- Per-wave reduction; one partial (or atomic) per wave.
    #pragma unroll
    for (int off = 32; off > 0; off >>= 1) lsum += __shfl_down(lsum, off, 64);
    if ((tid & 63) == 0) {
        const int wave = tid >> 6;
        const int bid = (blockIdx.z * NBLKY + blockIdx.y) * NBLKX + blockIdx.x;
        if (use_atomic) unsafeAtomicAdd(accum, lsum);
        else partial[bid * 4 + wave] = lsum;
    }
}

// Stage-1 reduce: 24 blocks x 1024 threads, each block sums a 1024-chunk.
__global__ __launch_bounds__(1024) void reduce1_kernel(
    const float* __restrict__ partial, float* __restrict__ bsum)
{
    __shared__ float ws[16];
    float s = partial[blockIdx.x * 1024 + threadIdx.x];
    #pragma unroll
    for (int off = 32; off > 0; off >>= 1) s += __shfl_down(s, off, 64);
    const int wave = threadIdx.x >> 6;
    if ((threadIdx.x & 63) == 0) ws[wave] = s;
    __syncthreads();
    if (threadIdx.x == 0) {
        float t = 0.f;
        #pragma unroll
        for (int i = 0; i < 16; i++) t += ws[i];
        bsum[blockIdx.x] = t;
    }
}

// Stage-2 reduce: one wave sums the 24 block sums and divides.
__global__ void reduce2_kernel(const float* __restrict__ bsum, float* __restrict__ out)
{
    float s = (threadIdx.x < NRB) ? bsum[threadIdx.x] : 0.f;
    #pragma unroll
    for (int off = 32; off > 0; off >>= 1) s += __shfl_down(s, off, 64);
    if (threadIdx.x == 0) out[0] = s * (1.0f / (float)NVALID);
}

__global__ void finalize_kernel(const float* __restrict__ accum, float* __restrict__ out) {
    out[0] = accum[0] * (1.0f / (float)NVALID);
}

extern "C" void kernel_launch(void* const* d_in, const int* in_sizes, int n_in,
                              void* d_out, int out_size, void* d_ws, size_t ws_size,
                              hipStream_t stream) {
    const float* x = (const float*)d_in[0];
    const float* y = (const float*)d_in[1];
    float* out = (float*)d_out;
    float* ws = (float*)d_ws;

    // Gaussian window, computed in double like the numpy reference, cast to f32.
    Weights wt;
    {
        double g[11], s = 0.0;
        for (int i = 0; i < 11; i++) {
            double d = (double)(i - 5);
            g[i] = exp(-(d * d) / (2.0 * 1.5 * 1.5));
            s += g[i];
        }
        for (int i = 0; i < 11; i++) wt.g[i] = (float)(g[i] / s);
    }

    dim3 grid(NBLKX, NBLKY, 48);
    const size_t need = (size_t)(NPART + NRB) * sizeof(float);
    const int use_atomic = (ws_size < need) ? 1 : 0;
    if (use_atomic) {
        hipMemsetAsync(ws, 0, sizeof(float), stream);
        ssim_kernel<<<grid, 256, 0, stream>>>(x, y, ws, ws, 1, wt);
        finalize_kernel<<<1, 1, 0, stream>>>(ws, out);
    } else {
        float* bsum = ws + NPART;
        ssim_kernel<<<grid, 256, 0, stream>>>(x, y, ws, ws, 0, wt);
        reduce1_kernel<<<NRB, 1024, 0, stream>>>(ws, bsum);
        reduce2_kernel<<<1, 64, 0, stream>>>(bsum, out);
    }
}